// Round 1
// baseline (349.995 us; speedup 1.0000x reference)
//
#include <hip/hip_runtime.h>
#include <hip/hip_bf16.h>
#include <math.h>

#define NP 512
#define NW 3584
#define NT 4096
#define FIN 256
#define H1 8
#define O1 32
#define H2 8
#define O2 256
#define NEG 0.2f

typedef __attribute__((ext_vector_type(8))) short bf16x8;
typedef __attribute__((ext_vector_type(4))) float f32x4;

__device__ __forceinline__ unsigned short f2bf(float f) {
    unsigned u = __float_as_uint(f);
    unsigned r = (u + 0x7FFF + ((u >> 16) & 1)) >> 16;
    return (unsigned short)r;
}

// ---- convert word_feature rows 0..3583 of hiddn_wp to bf16 ----
__global__ void k_conv_word(const float* __restrict__ wf, unsigned short* __restrict__ abf) {
    int i = blockIdx.x * 256 + threadIdx.x;
    if (i < NW * FIN) abf[i] = f2bf(wf[i]);
}

// ---- GAT1: h_prime1 [512][256] (col = h*32+o) + score dots ----
__global__ __launch_bounds__(256) void k_gat1_hp(
    const float* __restrict__ pf, const float* __restrict__ w1,
    const float* __restrict__ a_src1, const float* __restrict__ a_dst1,
    float* __restrict__ hp1, float* __restrict__ ss1, float* __restrict__ sd1)
{
    __shared__ float feat[8][FIN];
    int t = threadIdx.x;
    int n0 = blockIdx.x * 8;
    for (int q = 0; q < 8; q++) {
        int idx = q * 256 + t;
        feat[idx >> 8][idx & 255] = pf[(n0 + (idx >> 8)) * FIN + (idx & 255)];
    }
    __syncthreads();
    int h = t >> 5, o = t & 31;
    float acc[8] = {0,0,0,0,0,0,0,0};
    const float* wcol = w1 + h * FIN * O1 + o;
    for (int f = 0; f < FIN; f++) {
        float w = wcol[f * O1];
        #pragma unroll
        for (int i = 0; i < 8; i++) acc[i] += feat[i][f] * w;
    }
    float as = a_src1[h * O1 + o];
    float ad = a_dst1[h * O1 + o];
    #pragma unroll
    for (int i = 0; i < 8; i++) {
        hp1[(n0 + i) * 256 + t] = acc[i];
        float th = tanhf(acc[i]);
        float vs = th * as, vd = th * ad;
        #pragma unroll
        for (int off = 1; off < 32; off <<= 1) {
            vs += __shfl_xor(vs, off);
            vd += __shfl_xor(vd, off);
        }
        if (o == 0) { ss1[h * NP + n0 + i] = vs; sd1[h * NP + n0 + i] = vd; }
    }
}

// ---- GAT1 attention: 4 query rows per block; writes hiddn_wp rows 3584.. as bf16 ----
__global__ __launch_bounds__(256) void k_gat1_attn(
    const int* __restrict__ adj, const float* __restrict__ hp1,
    const float* __restrict__ ss1, const float* __restrict__ sd1,
    const float* __restrict__ b1, unsigned short* __restrict__ abf)
{
    __shared__ float p[4][H1][NP];   // 64 KB
    __shared__ float den[4][H1];
    int t = threadIdx.x;
    int n0 = blockIdx.x * 4;
    for (int r = 0; r < 64; r++) {
        int idx = r * 256 + t;
        int i = idx >> 12, h = (idx >> 9) & 7, m = idx & 511;
        float a = adj[(n0 + i) * NP + m] > 0 ? 1.0f : 0.0f;
        float e = ss1[h * NP + n0 + i] + sd1[h * NP + m];
        e = e >= 0.f ? e : NEG * e;
        // scores are bounded (|s|<~14 worst case) -> exp safe without max-subtraction
        p[i][h][m] = a * __expf(e);
    }
    __syncthreads();
    int w = t >> 6, l = t & 63;
    {
        int i = w;  // wave w reduces row-block i over all heads
        for (int h = 0; h < H1; h++) {
            float s = 0;
            #pragma unroll
            for (int q = 0; q < 8; q++) s += p[i][h][l + 64 * q];
            #pragma unroll
            for (int off = 1; off < 64; off <<= 1) s += __shfl_xor(s, off);
            if (l == 0) den[i][h] = s;
        }
    }
    __syncthreads();
    int h = t >> 5, o = t & 31;
    float acc[4] = {0,0,0,0};
    for (int m = 0; m < NP; m++) {
        float v = hp1[m * 256 + t];
        #pragma unroll
        for (int i = 0; i < 4; i++) acc[i] += p[i][h][m] * v;
    }
    float bo = b1[o];
    #pragma unroll
    for (int i = 0; i < 4; i++) {
        float r = acc[i] / den[i][h] + bo;
        r = r > 0.f ? r : expm1f(r);   // elu
        abf[(NW + n0 + i) * FIN + t] = f2bf(r);
    }
}

// ---- transpose+convert w2 [h][f][o] -> bf16 Bt [h][o][f] ----
__global__ void k_conv_w2(const float* __restrict__ w2, unsigned short* __restrict__ btbf) {
    int idx = blockIdx.x * 256 + threadIdx.x;
    int f = idx & 255, o = (idx >> 8) & 255, h = idx >> 16;
    btbf[idx] = f2bf(w2[(h * FIN + f) * O2 + o]);
}

// ---- hp2[h][m][o] = hiddn_wp @ w2[h], bf16 MFMA, 128x128 block tiles ----
__global__ __launch_bounds__(256) void k_gemm_hp2(
    const unsigned short* __restrict__ abf, const unsigned short* __restrict__ btbf,
    float* __restrict__ hp2)
{
    int bid = blockIdx.x;
    int h = bid >> 6;
    int rem = bid & 63;
    int mt = rem >> 1, nt = rem & 1;
    int w = threadIdx.x >> 6, l = threadIdx.x & 63;
    int m0 = mt * 128 + (w >> 1) * 64;
    int n0 = nt * 128 + (w & 1) * 64;
    int lr = l & 15, lq = l >> 4;
    const unsigned short* bbase = btbf + h * O2 * FIN;
    f32x4 acc[4][4];
    #pragma unroll
    for (int i = 0; i < 4; i++)
        #pragma unroll
        for (int j = 0; j < 4; j++) acc[i][j] = (f32x4){0.f, 0.f, 0.f, 0.f};
    for (int k = 0; k < FIN; k += 32) {
        bf16x8 a[4], b[4];
        int kc = k + lq * 8;
        #pragma unroll
        for (int i = 0; i < 4; i++)
            a[i] = *(const bf16x8*)(abf + (m0 + i * 16 + lr) * FIN + kc);
        #pragma unroll
        for (int j = 0; j < 4; j++)
            b[j] = *(const bf16x8*)(bbase + (n0 + j * 16 + lr) * FIN + kc);
        #pragma unroll
        for (int i = 0; i < 4; i++)
            #pragma unroll
            for (int j = 0; j < 4; j++)
                acc[i][j] = __builtin_amdgcn_mfma_f32_16x16x32_bf16(a[i], b[j], acc[i][j], 0, 0, 0);
    }
    float* out = hp2 + (size_t)h * NT * O2;
    #pragma unroll
    for (int i = 0; i < 4; i++)
        #pragma unroll
        for (int j = 0; j < 4; j++)
            #pragma unroll
            for (int r = 0; r < 4; r++)
                out[(m0 + i * 16 + lq * 4 + r) * O2 + n0 + j * 16 + lr] = acc[i][j][r];
}

// ---- per (h,m): s_src2, s_dst2, G[j]=hp2 . W_fc[:,j] ----
__global__ __launch_bounds__(256) void k_reduce_hp2(
    const float* __restrict__ hp2,
    const float* __restrict__ a_src2, const float* __restrict__ a_dst2,
    const float* __restrict__ W_fc,
    float* __restrict__ ss2, float* __restrict__ sd2, float* __restrict__ G)
{
    int t = threadIdx.x;
    int m = blockIdx.x & (NT - 1);
    int h = blockIdx.x >> 12;
    float x = hp2[((size_t)h * NT + m) * O2 + t];
    float th = tanhf(x);
    float v[7];
    v[0] = th * a_src2[h * O2 + t];
    v[1] = th * a_dst2[h * O2 + t];
    #pragma unroll
    for (int j = 0; j < 5; j++) v[j + 2] = x * W_fc[t * 5 + j];
    #pragma unroll
    for (int off = 1; off < 64; off <<= 1)
        #pragma unroll
        for (int q = 0; q < 7; q++) v[q] += __shfl_xor(v[q], off);
    __shared__ float red[4][7];
    int w = t >> 6, l = t & 63;
    if (l == 0) { for (int q = 0; q < 7; q++) red[w][q] = v[q]; }
    __syncthreads();
    if (t == 0) {
        float s[7];
        #pragma unroll
        for (int q = 0; q < 7; q++) s[q] = red[0][q] + red[1][q] + red[2][q] + red[3][q];
        ss2[h * NT + m] = s[0];
        sd2[h * NT + m] = s[1];
        #pragma unroll
        for (int j = 0; j < 5; j++) G[(h * 5 + j) * NT + m] = s[j + 2];
    }
}

// ---- c[j] = b2 . W_fc[:,j] ----
__global__ void k_cvec(const float* __restrict__ b2, const float* __restrict__ W_fc,
                       float* __restrict__ c) {
    int t = threadIdx.x;
    float v[5];
    #pragma unroll
    for (int j = 0; j < 5; j++) v[j] = b2[t] * W_fc[t * 5 + j];
    #pragma unroll
    for (int off = 1; off < 64; off <<= 1)
        #pragma unroll
        for (int j = 0; j < 5; j++) v[j] += __shfl_xor(v[j], off);
    __shared__ float red[4][5];
    int w = t >> 6, l = t & 63;
    if (l == 0) { for (int j = 0; j < 5; j++) red[w][j] = v[j]; }
    __syncthreads();
    if (t == 0)
        for (int j = 0; j < 5; j++) c[j] = red[0][j] + red[1][j] + red[2][j] + red[3][j];
}

// ---- GAT2 attention, fused with G: hf[n][j] = (1/8) sum_h softmax(row) . G[h][:][j] ----
__global__ __launch_bounds__(512) void k_gat2_attn(
    const int* __restrict__ adj, const float* __restrict__ ss2,
    const float* __restrict__ sd2, const float* __restrict__ G,
    float* __restrict__ hf)
{
    __shared__ float adjf[8][256];
    __shared__ float red[8][8][5];
    int t = threadIdx.x;
    int n0 = blockIdx.x * 8;
    int h = t >> 6, l = t & 63;   // wave == head
    float ss[8];
    #pragma unroll
    for (int i = 0; i < 8; i++) ss[i] = ss2[h * NT + n0 + i];
    const float* sdh = sd2 + h * NT;
    const float* g0 = G + (h * 5 + 0) * NT;
    const float* g1 = G + (h * 5 + 1) * NT;
    const float* g2 = G + (h * 5 + 2) * NT;
    const float* g3 = G + (h * 5 + 3) * NT;
    const float* g4 = G + (h * 5 + 4) * NT;
    float den[8] = {0,0,0,0,0,0,0,0};
    float num[8][5] = {{0}};
    for (int cb = 0; cb < NT; cb += 256) {
        #pragma unroll
        for (int q = 0; q < 4; q++) {
            int idx = q * 512 + t;
            int i = idx >> 8, mm = idx & 255;
            adjf[i][mm] = adj[(size_t)(n0 + i) * NT + cb + mm] > 0 ? 1.0f : 0.0f;
        }
        __syncthreads();
        #pragma unroll
        for (int q = 0; q < 4; q++) {
            int m = cb + q * 64 + l;
            float sd = sdh[m];
            float ga = g0[m], gb = g1[m], gc = g2[m], gd = g3[m], ge = g4[m];
            #pragma unroll
            for (int i = 0; i < 8; i++) {
                float e = ss[i] + sd;
                e = e >= 0.f ? e : NEG * e;
                float pp = adjf[i][q * 64 + l] * __expf(e);  // bounded scores: no max needed
                den[i] += pp;
                num[i][0] += pp * ga;
                num[i][1] += pp * gb;
                num[i][2] += pp * gc;
                num[i][3] += pp * gd;
                num[i][4] += pp * ge;
            }
        }
        __syncthreads();
    }
    #pragma unroll
    for (int i = 0; i < 8; i++) {
        #pragma unroll
        for (int off = 1; off < 64; off <<= 1) den[i] += __shfl_xor(den[i], off);
        #pragma unroll
        for (int j = 0; j < 5; j++)
            #pragma unroll
            for (int off = 1; off < 64; off <<= 1) num[i][j] += __shfl_xor(num[i][j], off);
    }
    if (l == 0) {
        #pragma unroll
        for (int i = 0; i < 8; i++) {
            float inv = 1.0f / den[i];
            #pragma unroll
            for (int j = 0; j < 5; j++) red[h][i][j] = num[i][j] * inv;
        }
    }
    __syncthreads();
    if (t < 40) {
        int i = t / 5, j = t % 5;
        float s = 0;
        #pragma unroll
        for (int ww = 0; ww < 8; ww++) s += red[ww][i][j];
        hf[(n0 + i) * 5 + j] = 0.125f * s;
    }
}

// ---- out[b][j] = (input[b].hf[:,j]) / sum(input[b]) + c[j] + b_fc[j] ----
__global__ __launch_bounds__(256) void k_final(
    const float* __restrict__ input, const float* __restrict__ hf,
    const float* __restrict__ cvec, const float* __restrict__ b_fc,
    float* __restrict__ out)
{
    int b = blockIdx.x, t = threadIdx.x;
    const float* row = input + (size_t)b * NW;
    float s = 0.f, a[5] = {0.f, 0.f, 0.f, 0.f, 0.f};
    for (int n = t; n < NW; n += 256) {
        float x = row[n];
        s += x;
        #pragma unroll
        for (int j = 0; j < 5; j++) a[j] += x * hf[n * 5 + j];
    }
    #pragma unroll
    for (int off = 1; off < 64; off <<= 1) {
        s += __shfl_xor(s, off);
        #pragma unroll
        for (int j = 0; j < 5; j++) a[j] += __shfl_xor(a[j], off);
    }
    __shared__ float red[4][6];
    int w = t >> 6, l = t & 63;
    if (l == 0) { red[w][0] = s; for (int j = 0; j < 5; j++) red[w][j + 1] = a[j]; }
    __syncthreads();
    if (t < 5) {
        float st = red[0][0] + red[1][0] + red[2][0] + red[3][0];
        float aj = red[0][t + 1] + red[1][t + 1] + red[2][t + 1] + red[3][t + 1];
        out[b * 5 + t] = aj / st + cvec[t] + b_fc[t];
    }
}

extern "C" void kernel_launch(void* const* d_in, const int* in_sizes, int n_in,
                              void* d_out, int out_size, void* d_ws, size_t ws_size,
                              hipStream_t stream) {
    const float* input   = (const float*)d_in[0];
    const float* pf      = (const float*)d_in[1];
    const float* wf      = (const float*)d_in[2];
    const float* w1      = (const float*)d_in[3];
    const float* a_src1  = (const float*)d_in[4];
    const float* a_dst1  = (const float*)d_in[5];
    const float* b1      = (const float*)d_in[6];
    const float* w2      = (const float*)d_in[7];
    const float* a_src2  = (const float*)d_in[8];
    const float* a_dst2  = (const float*)d_in[9];
    const float* b2      = (const float*)d_in[10];
    const float* W_fc    = (const float*)d_in[11];
    const float* b_fc    = (const float*)d_in[12];
    const int* pern_adj  = (const int*)d_in[13];
    const int* wp_adj    = (const int*)d_in[14];
    float* out = (float*)d_out;

    char* ws = (char*)d_ws;
    float*          hp2  = (float*)(ws);                      // 32 MB
    unsigned short* abf  = (unsigned short*)(ws + 33554432);  // 2 MB
    unsigned short* btbf = (unsigned short*)(ws + 35651584);  // 1 MB
    float*          hp1  = (float*)(ws + 36700160);           // 512 KB
    float*          ss1  = (float*)(ws + 37224448);           // 16 KB
    float*          sd1  = (float*)(ws + 37240832);           // 16 KB
    float*          ss2  = (float*)(ws + 37257216);           // 128 KB
    float*          sd2  = (float*)(ws + 37388288);           // 128 KB
    float*          G    = (float*)(ws + 37519360);           // 640 KB
    float*          hf   = (float*)(ws + 38174720);           // 70 KB
    float*          cvec = (float*)(ws + 38246400);           // 32 B

    k_conv_word<<<3584, 256, 0, stream>>>(wf, abf);
    k_gat1_hp<<<64, 256, 0, stream>>>(pf, w1, a_src1, a_dst1, hp1, ss1, sd1);
    k_gat1_attn<<<128, 256, 0, stream>>>(pern_adj, hp1, ss1, sd1, b1, abf);
    k_conv_w2<<<2048, 256, 0, stream>>>(w2, btbf);
    k_gemm_hp2<<<512, 256, 0, stream>>>(abf, btbf, hp2);
    k_reduce_hp2<<<32768, 256, 0, stream>>>(hp2, a_src2, a_dst2, W_fc, ss2, sd2, G);
    k_cvec<<<1, 256, 0, stream>>>(b2, W_fc, cvec);
    k_gat2_attn<<<448, 512, 0, stream>>>(wp_adj, ss2, sd2, G, hf);
    k_final<<<1024, 256, 0, stream>>>(input, hf, cvec, b_fc, out);
}

// Round 2
// 297.122 us; speedup vs baseline: 1.1780x; 1.1780x over previous
//
#include <hip/hip_runtime.h>
#include <hip/hip_bf16.h>
#include <math.h>

#define NP 512
#define NW 3584
#define NT 4096
#define FIN 256
#define H1 8
#define O1 32
#define H2 8
#define O2 256
#define NEG 0.2f

typedef __attribute__((ext_vector_type(8))) short bf16x8;
typedef __attribute__((ext_vector_type(4))) float f32x4;

__device__ __forceinline__ unsigned short f2bf(float f) {
    unsigned u = __float_as_uint(f);
    unsigned r = (u + 0x7FFF + ((u >> 16) & 1)) >> 16;
    return (unsigned short)r;
}

// ---- convert word_feature rows 0..3583 of hiddn_wp to bf16 ----
__global__ void k_conv_word(const float* __restrict__ wf, unsigned short* __restrict__ abf) {
    int i = blockIdx.x * 256 + threadIdx.x;
    if (i < NW * FIN) abf[i] = f2bf(wf[i]);
}

// ---- GAT1: h_prime1 [512][256] (col = h*32+o) + score dots ----
__global__ __launch_bounds__(256) void k_gat1_hp(
    const float* __restrict__ pf, const float* __restrict__ w1,
    const float* __restrict__ a_src1, const float* __restrict__ a_dst1,
    float* __restrict__ hp1, float* __restrict__ ss1, float* __restrict__ sd1)
{
    __shared__ float feat[8][FIN];
    int t = threadIdx.x;
    int n0 = blockIdx.x * 8;
    for (int q = 0; q < 8; q++) {
        int idx = q * 256 + t;
        feat[idx >> 8][idx & 255] = pf[(n0 + (idx >> 8)) * FIN + (idx & 255)];
    }
    __syncthreads();
    int h = t >> 5, o = t & 31;
    float acc[8] = {0,0,0,0,0,0,0,0};
    const float* wcol = w1 + h * FIN * O1 + o;
    for (int f = 0; f < FIN; f++) {
        float w = wcol[f * O1];
        #pragma unroll
        for (int i = 0; i < 8; i++) acc[i] += feat[i][f] * w;
    }
    float as = a_src1[h * O1 + o];
    float ad = a_dst1[h * O1 + o];
    #pragma unroll
    for (int i = 0; i < 8; i++) {
        hp1[(n0 + i) * 256 + t] = acc[i];
        float th = tanhf(acc[i]);
        float vs = th * as, vd = th * ad;
        #pragma unroll
        for (int off = 1; off < 32; off <<= 1) {
            vs += __shfl_xor(vs, off);
            vd += __shfl_xor(vd, off);
        }
        if (o == 0) { ss1[h * NP + n0 + i] = vs; sd1[h * NP + n0 + i] = vd; }
    }
}

// ---- GAT1 attention: 2 query rows per block (256 blocks); writes hiddn_wp rows 3584.. as bf16 ----
__global__ __launch_bounds__(256) void k_gat1_attn(
    const int* __restrict__ adj, const float* __restrict__ hp1,
    const float* __restrict__ ss1, const float* __restrict__ sd1,
    const float* __restrict__ b1, unsigned short* __restrict__ abf)
{
    __shared__ float p[2][H1][NP];   // 32 KB
    __shared__ float den[2][H1];
    int t = threadIdx.x;
    int n0 = blockIdx.x * 2;
    for (int rr = 0; rr < 32; rr++) {
        int idx = rr * 256 + t;       // 8192 entries: i(1) h(3) m(9)
        int i = idx >> 12, h = (idx >> 9) & 7, m = idx & 511;
        float a = adj[(n0 + i) * NP + m] > 0 ? 1.0f : 0.0f;
        float e = ss1[h * NP + n0 + i] + sd1[h * NP + m];
        e = fmaxf(e, NEG * e);
        p[i][h][m] = a * __expf(e);   // bounded scores: no max-subtraction needed
    }
    __syncthreads();
    int w = t >> 6, l = t & 63;
    {
        int i = w & 1;
        #pragma unroll
        for (int hh = 0; hh < 4; hh++) {
            int h = (w >> 1) * 4 + hh;
            float s = 0;
            #pragma unroll
            for (int q = 0; q < 8; q++) s += p[i][h][l + 64 * q];
            #pragma unroll
            for (int off = 1; off < 64; off <<= 1) s += __shfl_xor(s, off);
            if (l == 0) den[i][h] = s;
        }
    }
    __syncthreads();
    int h = t >> 5, o = t & 31;
    float acc[2] = {0, 0};
    #pragma unroll 4
    for (int m = 0; m < NP; m++) {
        float v = hp1[m * 256 + t];
        acc[0] += p[0][h][m] * v;
        acc[1] += p[1][h][m] * v;
    }
    float bo = b1[o];
    #pragma unroll
    for (int i = 0; i < 2; i++) {
        float r = acc[i] / den[i][h] + bo;
        r = r > 0.f ? r : expm1f(r);   // elu
        abf[(NW + n0 + i) * FIN + t] = f2bf(r);
    }
}

// ---- transpose+convert w2 [h][f][o] -> bf16 Bt [h][o][f] ----
__global__ void k_conv_w2(const float* __restrict__ w2, unsigned short* __restrict__ btbf) {
    int idx = blockIdx.x * 256 + threadIdx.x;
    int f = idx & 255, o = (idx >> 8) & 255, h = idx >> 16;
    btbf[idx] = f2bf(w2[(h * FIN + f) * O2 + o]);
}

// ---- pack wp_adj rows 0..3583 into bitmasks: packed[n][chunk] bit l = adj[n][chunk*64+l] ----
__global__ __launch_bounds__(256) void k_pack_adj(const int* __restrict__ adj,
                                                  unsigned long long* __restrict__ packed) {
    int w = threadIdx.x >> 6, l = threadIdx.x & 63;
    int r = blockIdx.x * 4 + w;
    const int* row = adj + (size_t)r * NT;
    unsigned long long myword = 0;
    for (int chunk = 0; chunk < 64; chunk++) {
        unsigned long long mask = __ballot(row[chunk * 64 + l] != 0);
        if (l == chunk) myword = mask;
    }
    packed[r * 64 + l] = myword;
}

// ---- hp2 GEMM with FUSED ss2/sd2/G reduction epilogue (hp2 never materialized) ----
// gpart[h][slice(4)][m][8]: {ss, sd, G0..G4, pad} partial over 64-col slice
__global__ __launch_bounds__(256) void k_gemm_hp2(
    const unsigned short* __restrict__ abf, const unsigned short* __restrict__ btbf,
    const float* __restrict__ a_src2, const float* __restrict__ a_dst2,
    const float* __restrict__ W_fc, float* __restrict__ gpart)
{
    int bid = blockIdx.x;
    int h = bid >> 6;
    int rem = bid & 63;
    int mt = rem >> 1, nt = rem & 1;
    int w = threadIdx.x >> 6, l = threadIdx.x & 63;
    int m0 = mt * 128 + (w >> 1) * 64;
    int n0 = nt * 128 + (w & 1) * 64;
    int lr = l & 15, lq = l >> 4;
    const unsigned short* bbase = btbf + h * O2 * FIN;
    f32x4 acc[4][4];
    #pragma unroll
    for (int i = 0; i < 4; i++)
        #pragma unroll
        for (int j = 0; j < 4; j++) acc[i][j] = (f32x4){0.f, 0.f, 0.f, 0.f};
    for (int k = 0; k < FIN; k += 32) {
        bf16x8 a[4], b[4];
        int kc = k + lq * 8;
        #pragma unroll
        for (int i = 0; i < 4; i++)
            a[i] = *(const bf16x8*)(abf + (m0 + i * 16 + lr) * FIN + kc);
        #pragma unroll
        for (int j = 0; j < 4; j++)
            b[j] = *(const bf16x8*)(bbase + (n0 + j * 16 + lr) * FIN + kc);
        #pragma unroll
        for (int i = 0; i < 4; i++)
            #pragma unroll
            for (int j = 0; j < 4; j++)
                acc[i][j] = __builtin_amdgcn_mfma_f32_16x16x32_bf16(a[i], b[j], acc[i][j], 0, 0, 0);
    }
    // epilogue: per row m, partial sums over this wave's 64 columns
    int slice = nt * 2 + (w & 1);
    float as[4], ad[4], wfc[4][5];
    #pragma unroll
    for (int j = 0; j < 4; j++) {
        int col = n0 + j * 16 + lr;
        as[j] = a_src2[h * O2 + col];
        ad[j] = a_dst2[h * O2 + col];
        #pragma unroll
        for (int jj = 0; jj < 5; jj++) wfc[j][jj] = W_fc[col * 5 + jj];
    }
    float* base = gpart + ((size_t)h * 4 + slice) * NT * 8;
    #pragma unroll
    for (int i = 0; i < 4; i++) {
        #pragma unroll
        for (int r = 0; r < 4; r++) {
            float s[7] = {0,0,0,0,0,0,0};
            #pragma unroll
            for (int j = 0; j < 4; j++) {
                float x = acc[i][j][r];
                float th = tanhf(x);
                s[0] += th * as[j];
                s[1] += th * ad[j];
                #pragma unroll
                for (int jj = 0; jj < 5; jj++) s[2 + jj] += x * wfc[j][jj];
            }
            #pragma unroll
            for (int off = 1; off < 16; off <<= 1)
                #pragma unroll
                for (int q = 0; q < 7; q++) s[q] += __shfl_xor(s[q], off);
            if (lr == 0) {
                int m = m0 + i * 16 + lq * 4 + r;
                float* dst = base + (size_t)m * 8;
                #pragma unroll
                for (int q = 0; q < 7; q++) dst[q] = s[q];
            }
        }
    }
}

// ---- combine the 4 column-slices -> ss2, sd2, G ----
__global__ __launch_bounds__(256) void k_comb_hp2(
    const float* __restrict__ gpart,
    float* __restrict__ ss2, float* __restrict__ sd2, float* __restrict__ G)
{
    int idx = blockIdx.x * 256 + threadIdx.x;   // h*NT + m
    int h = idx >> 12, m = idx & (NT - 1);
    float s[7] = {0,0,0,0,0,0,0};
    #pragma unroll
    for (int sl = 0; sl < 4; sl++) {
        const float* p = gpart + (((size_t)h * 4 + sl) * NT + m) * 8;
        #pragma unroll
        for (int q = 0; q < 7; q++) s[q] += p[q];
    }
    ss2[h * NT + m] = s[0];
    sd2[h * NT + m] = s[1];
    #pragma unroll
    for (int j = 0; j < 5; j++) G[(h * 5 + j) * NT + m] = s[2 + j];
}

// ---- c[j] = b2 . W_fc[:,j] ----
__global__ void k_cvec(const float* __restrict__ b2, const float* __restrict__ W_fc,
                       float* __restrict__ c) {
    int t = threadIdx.x;
    float v[5];
    #pragma unroll
    for (int j = 0; j < 5; j++) v[j] = b2[t] * W_fc[t * 5 + j];
    #pragma unroll
    for (int off = 1; off < 64; off <<= 1)
        #pragma unroll
        for (int j = 0; j < 5; j++) v[j] += __shfl_xor(v[j], off);
    __shared__ float red[4][5];
    int w = t >> 6, l = t & 63;
    if (l == 0) { for (int j = 0; j < 5; j++) red[w][j] = v[j]; }
    __syncthreads();
    if (t == 0)
        for (int j = 0; j < 5; j++) c[j] = red[0][j] + red[1][j] + red[2][j] + red[3][j];
}

// ---- GAT2 attention, m-split x4, bit-packed adj, partial den/num out ----
// part[((c*448+nb)*64 + h*8 + i)*6 + {den,num0..4}]
__global__ __launch_bounds__(512) void k_gat2_attn(
    const unsigned long long* __restrict__ packed, const float* __restrict__ ss2,
    const float* __restrict__ sd2, const float* __restrict__ G,
    float* __restrict__ part)
{
    int t = threadIdx.x;
    int h = t >> 6, l = t & 63;   // wave == head
    int nb = blockIdx.x & 511;    // actually % 448 via launch: grid = c*448+nb
    int c;
    { int b = blockIdx.x; c = b / 448; nb = b - c * 448; }
    int n0 = nb * 8;
    float ss[8];
    #pragma unroll
    for (int i = 0; i < 8; i++) ss[i] = ss2[h * NT + n0 + i];
    const float* sdh = sd2 + h * NT;
    const float* g0 = G + (h * 5 + 0) * NT;
    const float* g1 = G + (h * 5 + 1) * NT;
    const float* g2 = G + (h * 5 + 2) * NT;
    const float* g3 = G + (h * 5 + 3) * NT;
    const float* g4 = G + (h * 5 + 4) * NT;
    float den[8] = {0,0,0,0,0,0,0,0};
    float num[8][5] = {{0}};
    int mbase = c * 1024;
    int cbase = mbase >> 6;
    for (int q = 0; q < 16; q++) {
        int m = mbase + q * 64 + l;
        float sd = sdh[m];
        float ga = g0[m], gb = g1[m], gc = g2[m], gd = g3[m], ge = g4[m];
        #pragma unroll
        for (int i = 0; i < 8; i++) {
            unsigned long long word = packed[(size_t)(n0 + i) * 64 + cbase + q];
            float e = ss[i] + sd;
            e = fmaxf(e, NEG * e);
            float t0 = __expf(e);
            float pp = ((word >> l) & 1ull) ? t0 : 0.0f;
            den[i] += pp;
            num[i][0] += pp * ga;
            num[i][1] += pp * gb;
            num[i][2] += pp * gc;
            num[i][3] += pp * gd;
            num[i][4] += pp * ge;
        }
    }
    float* base = part + ((size_t)(c * 448 + nb) * 64 + h * 8) * 6;
    #pragma unroll
    for (int i = 0; i < 8; i++) {
        #pragma unroll
        for (int off = 1; off < 64; off <<= 1) {
            den[i] += __shfl_xor(den[i], off);
            #pragma unroll
            for (int j = 0; j < 5; j++) num[i][j] += __shfl_xor(num[i][j], off);
        }
        if (l == 0) {
            float* dst = base + i * 6;
            dst[0] = den[i];
            #pragma unroll
            for (int j = 0; j < 5; j++) dst[1 + j] = num[i][j];
        }
    }
}

// ---- combine chunks + heads -> hf[n][5] ----
__global__ __launch_bounds__(256) void k_gat2_comb(const float* __restrict__ part,
                                                   float* __restrict__ hf) {
    int idx = blockIdx.x * 256 + threadIdx.x;  // n*8 + h
    int n = idx >> 3, h = idx & 7;
    int nb = n >> 3, i = n & 7;
    float den = 0, num[5] = {0,0,0,0,0};
    #pragma unroll
    for (int cc = 0; cc < 4; cc++) {
        const float* p = part + ((size_t)(cc * 448 + nb) * 64 + h * 8 + i) * 6;
        den += p[0];
        #pragma unroll
        for (int j = 0; j < 5; j++) num[j] += p[1 + j];
    }
    float inv = 1.0f / (den * 8.0f);
    float v[5];
    #pragma unroll
    for (int j = 0; j < 5; j++) v[j] = num[j] * inv;
    #pragma unroll
    for (int off = 1; off < 8; off <<= 1)
        #pragma unroll
        for (int j = 0; j < 5; j++) v[j] += __shfl_xor(v[j], off);
    if (h == 0) {
        #pragma unroll
        for (int j = 0; j < 5; j++) hf[n * 5 + j] = v[j];
    }
}

// ---- out[b][j] = (input[b].hf[:,j]) / sum(input[b]) + c[j] + b_fc[j] ----
__global__ __launch_bounds__(256) void k_final(
    const float* __restrict__ input, const float* __restrict__ hf,
    const float* __restrict__ cvec, const float* __restrict__ b_fc,
    float* __restrict__ out)
{
    int b = blockIdx.x, t = threadIdx.x;
    const float* row = input + (size_t)b * NW;
    float s = 0.f, a[5] = {0.f, 0.f, 0.f, 0.f, 0.f};
    for (int n = t; n < NW; n += 256) {
        float x = row[n];
        s += x;
        #pragma unroll
        for (int j = 0; j < 5; j++) a[j] += x * hf[n * 5 + j];
    }
    #pragma unroll
    for (int off = 1; off < 64; off <<= 1) {
        s += __shfl_xor(s, off);
        #pragma unroll
        for (int j = 0; j < 5; j++) a[j] += __shfl_xor(a[j], off);
    }
    __shared__ float red[4][6];
    int w = t >> 6, l = t & 63;
    if (l == 0) { red[w][0] = s; for (int j = 0; j < 5; j++) red[w][j + 1] = a[j]; }
    __syncthreads();
    if (t < 5) {
        float st = red[0][0] + red[1][0] + red[2][0] + red[3][0];
        float aj = red[0][t + 1] + red[1][t + 1] + red[2][t + 1] + red[3][t + 1];
        out[b * 5 + t] = aj / st + cvec[t] + b_fc[t];
    }
}

extern "C" void kernel_launch(void* const* d_in, const int* in_sizes, int n_in,
                              void* d_out, int out_size, void* d_ws, size_t ws_size,
                              hipStream_t stream) {
    const float* input   = (const float*)d_in[0];
    const float* pf      = (const float*)d_in[1];
    const float* wf      = (const float*)d_in[2];
    const float* w1      = (const float*)d_in[3];
    const float* a_src1  = (const float*)d_in[4];
    const float* a_dst1  = (const float*)d_in[5];
    const float* b1      = (const float*)d_in[6];
    const float* w2      = (const float*)d_in[7];
    const float* a_src2  = (const float*)d_in[8];
    const float* a_dst2  = (const float*)d_in[9];
    const float* b2      = (const float*)d_in[10];
    const float* W_fc    = (const float*)d_in[11];
    const float* b_fc    = (const float*)d_in[12];
    const int* pern_adj  = (const int*)d_in[13];
    const int* wp_adj    = (const int*)d_in[14];
    float* out = (float*)d_out;

    char* ws = (char*)d_ws;
    unsigned short* abf    = (unsigned short*)(ws);            // 2 MB
    unsigned short* btbf   = (unsigned short*)(ws + 2097152);  // 1 MB
    float*          hp1    = (float*)(ws + 3145728);           // 512 KB
    float*          ss1    = (float*)(ws + 3670016);           // 16 KB
    float*          sd1    = (float*)(ws + 3686400);           // 16 KB
    float*          ss2    = (float*)(ws + 3702784);           // 128 KB
    float*          sd2    = (float*)(ws + 3833856);           // 128 KB
    float*          G      = (float*)(ws + 3964928);           // 640 KB
    float*          hf     = (float*)(ws + 4620288);           // 70 KB
    float*          cvec   = (float*)(ws + 4691968);           // 32 B
    unsigned long long* packed = (unsigned long long*)(ws + 4692480); // 1.75 MB
    float*          gpart  = (float*)(ws + 6527488);           // 4 MB
    float*          part   = (float*)(ws + 10721792);          // 2.625 MB

    k_conv_word<<<3584, 256, 0, stream>>>(wf, abf);
    k_gat1_hp<<<64, 256, 0, stream>>>(pf, w1, a_src1, a_dst1, hp1, ss1, sd1);
    k_gat1_attn<<<256, 256, 0, stream>>>(pern_adj, hp1, ss1, sd1, b1, abf);
    k_conv_w2<<<2048, 256, 0, stream>>>(w2, btbf);
    k_pack_adj<<<896, 256, 0, stream>>>(wp_adj, packed);
    k_gemm_hp2<<<512, 256, 0, stream>>>(abf, btbf, a_src2, a_dst2, W_fc, gpart);
    k_comb_hp2<<<128, 256, 0, stream>>>(gpart, ss2, sd2, G);
    k_cvec<<<1, 256, 0, stream>>>(b2, W_fc, cvec);
    k_gat2_attn<<<1792, 512, 0, stream>>>(packed, ss2, sd2, G, part);
    k_gat2_comb<<<112, 256, 0, stream>>>(part, hf);
    k_final<<<1024, 256, 0, stream>>>(input, hf, cvec, b_fc, out);
}